// Round 18
// baseline (352.372 us; speedup 1.0000x reference)
//
#include <hip/hip_runtime.h>
#include <hip/hip_bf16.h>
#include <stdint.h>
#include <stddef.h>

// Problem dims (fixed): B=64, C=128, H=W=56, 3x3 conv pad=1 stride=1.
#define CH 128
#define HH 56
#define WW 56
#define HWPIX (HH*WW)        // 3136
#define NB 64
#define NPIXF 200704.0f      // B*H*W
#define NCONVBLK 448         // 64 samples x 7 column tiles (56x8 px)
#define PSTR 72              // patch row stride in shorts (144B = 4-bank class)

typedef __attribute__((ext_vector_type(8))) short short8v;    // 8 bf16 -> MFMA A/B frag
typedef __attribute__((ext_vector_type(8))) unsigned short bfv8;
typedef __attribute__((ext_vector_type(4))) unsigned short bfv4;
typedef __attribute__((ext_vector_type(4))) float f32x4;

__device__ __forceinline__ unsigned short f2bf(float f) {
  unsigned int u = __float_as_uint(f);
  u += 0x7fffu + ((u >> 16) & 1u);            // RNE
  return (unsigned short)(u >> 16);
}
__device__ __forceinline__ float bf2f(unsigned short s) {
  return __uint_as_float(((unsigned int)s) << 16);
}

// ---------------------------------------------------------------------------
// K1: x NCHW fp32 -> NHWC bf16 (LDS transpose, coalesced 16B/lane writes).
__global__ __launch_bounds__(256)
void prep_x(const float* __restrict__ x, unsigned short* __restrict__ xT) {
  __shared__ unsigned short tile[4 * 56 * 128];
  const int bid = blockIdx.x;
  const int b = bid / 14, hq = bid % 14;
  const int hl = threadIdx.x >> 6;
  const int h = hq * 4 + hl;
  const int w = threadIdx.x & 63;
  if (w < WW) {
    const float* src = x + (size_t)b * CH * HWPIX + h * WW + w;
    const int pos = hl * WW + w;
    #pragma unroll 4
    for (int c0 = 0; c0 < CH; c0 += 8) {
      bfv8 v;
      #pragma unroll
      for (int k = 0; k < 8; ++k) v[k] = f2bf(src[(size_t)(c0 + k) * HWPIX]);
      const int idx = (pos * CH + c0) ^ ((pos & 7) << 3);
      *(bfv8*)(tile + idx) = v;
    }
  }
  __syncthreads();
  unsigned short* out = xT + (size_t)(b * HH + hq * 4) * WW * CH;
  #pragma unroll
  for (int j = 0; j < 14; ++j) {
    const int u = j * 256 + threadIdx.x;
    const int idx = (u * 8) ^ (((u >> 4) & 7) << 3);
    *(bfv8*)(out + u * 8) = *(const bfv8*)(tile + idx);
  }
}

// ---------------------------------------------------------------------------
// K2: weights [B,O,I,3,3] fp32 -> [B,tap,O,I] bf16 (dense reads, 16B writes).
__global__ __launch_bounds__(256)
void prep_w(const float* __restrict__ w1, const float* __restrict__ w2,
            unsigned short* __restrict__ o1, unsigned short* __restrict__ o2) {
  __shared__ unsigned short lw[18432];
  const int id = blockIdx.x;
  const int which = id >> 9;
  const int b = (id >> 3) & 63, ck = id & 7;
  const float* src = (which ? w2 : w1) + ((size_t)b * 16384 + ck * 2048) * 9;
  unsigned short* dst = (which ? o2 : o1);
  const int t = threadIdx.x;
  #pragma unroll
  for (int j = 0; j < 72; ++j)
    lw[j * 256 + t] = f2bf(src[j * 256 + t]);
  __syncthreads();
  const int ol = t >> 4, oct = t & 15;
  #pragma unroll
  for (int tap = 0; tap < 9; ++tap) {
    bfv8 v;
    #pragma unroll
    for (int k = 0; k < 8; ++k) v[k] = lw[(ol * 128 + oct * 8 + k) * 9 + tap];
    *(bfv8*)(dst + ((size_t)(b * 9 + tap) * CH + ck * 16 + ol) * CH + oct * 8) = v;
  }
}

// ---------------------------------------------------------------------------
// K3/K5: per-sample conv, implicit GEMM.
// R26: R25's 56x8 column tile / 8 waves x 16 O, with the PHASE-1 PIPELINE
// BUG FIXED. R25's absmax 2.85: phase 1 ran only RUN(18..31) (stages issued
// 20..33) but computed 34/35 -> 2 of 36 stages read never-staged wbuf
// garbage. Fix: phase 1 = RUN(18..33) (stages through 35) + the same
// vmcnt(1)/COMPUTE(34), vmcnt(0)/COMPUTE(35) tail as phase 0. Buffer
// parity: RUN(33)=STAGE(35,2), COMPUTE(33,0); tail bufs 1,2. Everything
// else identical to R25: blocks 448 (glls/CU 1008->504), acc[28]=112
// regs/wave, one 512-thr block/CU (8 waves = R22-equivalent residency),
// LDS 109KB, (512,2) budget ~128 arch.
// Predict: absmax pass; conv 87.5->75-83, MfmaUtil 29-34, FETCH ~36MB
// (>60 = spill = abort). Pre-committed: conv >= 86 or fail -> revert R24,
// declare ROOFLINE.
template<bool FUSE>
__global__ __launch_bounds__(512, 2)
void conv_kernel(const unsigned short* __restrict__ in,
                 const unsigned short* __restrict__ wt,
                 unsigned short* __restrict__ outp,
                 float* __restrict__ partials,
                 const float* __restrict__ tab) {   // [256]: scale | shift (FUSE)
  __shared__ __align__(16) unsigned short patch[580 * PSTR]; // 58 rows x 10 w
  __shared__ __align__(16) unsigned short wbuf[12288];   // 8 wv x 3 buf x 512
  __shared__ float sacc[256];                            // sum[128] | sumsq[128]
  const int xcd = blockIdx.x & 7;
  const int q = blockIdx.x >> 3;                    // 0..55
  const int s = q / 7;
  const int col = q - s * 7;                        // 0..6
  const int b = s * 8 + xcd;
  const int w0 = col * 8;
  const int t = threadIdx.x;

  const int lane = t & 63, wv = t >> 6;             // wv 0..7
  const int lrow = lane & 15, lgrp = lane >> 4;
  const int px = lrow & 7, pyl = lrow >> 3;

  if (t < 256) sacc[t] = 0.0f;

  // Per-lane global source = lane's A-frag: W[o=wv*16+lrow][lgrp*8..+8].
  const unsigned short* wsrc =
      wt + (size_t)b * 9 * CH * CH + (wv * 16 + lrow) * CH + lgrp * 8;

  // Stage S (0..35): phase = S/18, tap = (S%18)>>1, ic = phase*64+(S&1)*32.
  // 16 O x 32 I = 1KB/wave into wave-private buffer P (ONE gll instr).
#define STAGE(S, P) { \
    const unsigned short* g_ = wsrc + (((S) % 18) >> 1) * (CH * CH) + \
                               ((S) / 18) * 64 + ((S) & 1) * 32; \
    unsigned short* l_ = wbuf + (wv * 3 + (P)) * 512; \
    __builtin_amdgcn_global_load_lds( \
        (const __attribute__((address_space(1))) void*)g_, \
        (__attribute__((address_space(3))) void*)l_, 16, 0, 0); \
  }

  // Patch staging for channel-half PH: 580 positions x 64 ch (128B each).
  // pos u = dh*10+dw covers input (h = dh-1, w = w0+dw-1), dh 0..57.
#define STAGE_PATCH(PH) { \
    for (int u = t; u < 580; u += 512) { \
      const int dh = u / 10, dw = u - dh * 10; \
      const int h = dh - 1, w = w0 + dw - 1; \
      unsigned short* ld = &patch[u * PSTR]; \
      if (h >= 0 && h < HH && w >= 0 && w < WW) { \
        const unsigned short* src = \
            in + ((size_t)((b * HH + h) * WW + w)) * CH + (PH) * 64; \
        if (FUSE) { \
          for (int j = 0; j < 8; ++j) { \
            const bfv8 v = *(const bfv8*)(src + j * 8); \
            bfv8 o; \
            for (int k = 0; k < 8; ++k) { \
              const int c = (PH) * 64 + j * 8 + k; \
              o[k] = f2bf(fmaxf(bf2f(v[k]) * tab[c] + tab[CH + c], 0.0f)); \
            } \
            *(bfv8*)(ld + j * 8) = o; \
          } \
        } else { \
          for (int j = 0; j < 8; ++j) \
            *(bfv8*)(ld + j * 8) = *(const bfv8*)(src + j * 8); \
        } \
      } else { \
        const bfv8 z = {0, 0, 0, 0, 0, 0, 0, 0}; \
        for (int j = 0; j < 8; ++j) *(bfv8*)(ld + j * 8) = z; \
      } \
    } }

  // COMPUTE(S,P): 1 A-frag lane-linear from wave-private buf P,
  // 28 B-frags from patch, 28 MFMA (K=32 chunk icl of the 64-wide rows).
  // Output row r = nf*2+pyl (0..55); input pos = (r + tap/3)*10 + px + tap%3.
#define COMPUTE(S, P) { \
    const int tap_ = ((S) % 18) >> 1, icl_ = (S) & 1; \
    const int pb_ = (pyl + tap_ / 3) * 10 + px + tap_ % 3; \
    const unsigned short* ab_ = wbuf + (wv * 3 + (P)) * 512 + lane * 8; \
    const short8v a0_ = *(const short8v*)(ab_); \
    _Pragma("unroll") \
    for (int nf = 0; nf < 28; ++nf) { \
      const short8v bfr = *(const short8v*)( \
          &patch[(pb_ + nf * 20) * PSTR + icl_ * 32 + lgrp * 8]); \
      acc[nf] = __builtin_amdgcn_mfma_f32_16x16x32_bf16(a0_, bfr, acc[nf], 0, 0, 0); \
    } }

#define RUN(S) \
    __builtin_amdgcn_sched_barrier(0); \
    STAGE((S) + 2, ((S) + 2) % 3) \
    asm volatile("s_waitcnt vmcnt(2)" ::: "memory"); \
    __builtin_amdgcn_sched_barrier(0); \
    COMPUTE(S, (S) % 3)

  // ---- Phase 0: I in [0,64) ----
  STAGE(0, 0)
  STAGE_PATCH(0)
  __syncthreads();

  f32x4 acc[28];
  #pragma unroll
  for (int n = 0; n < 28; ++n) acc[n] = (f32x4){0.f, 0.f, 0.f, 0.f};

  STAGE(1, 1)
  RUN(0)  RUN(1)  RUN(2)  RUN(3)  RUN(4)  RUN(5)  RUN(6)  RUN(7)
  RUN(8)  RUN(9)  RUN(10) RUN(11) RUN(12) RUN(13) RUN(14) RUN(15)
  __builtin_amdgcn_sched_barrier(0);
  asm volatile("s_waitcnt vmcnt(1)" ::: "memory");
  __builtin_amdgcn_sched_barrier(0);
  COMPUTE(16, 1)
  __builtin_amdgcn_sched_barrier(0);
  asm volatile("s_waitcnt vmcnt(0)" ::: "memory");
  __builtin_amdgcn_sched_barrier(0);
  COMPUTE(17, 2)

  // ---- Phase boundary: restage patch with I in [64,128) ----
  STAGE(18, 0)            // drained resident by the barrier below
  __syncthreads();        // all phase-0 patch reads done
  STAGE_PATCH(1)
  __syncthreads();        // new patch ready

  STAGE(19, 1)
  RUN(18) RUN(19) RUN(20) RUN(21) RUN(22) RUN(23) RUN(24) RUN(25)
  RUN(26) RUN(27) RUN(28) RUN(29) RUN(30) RUN(31) RUN(32) RUN(33)
  __builtin_amdgcn_sched_barrier(0);
  asm volatile("s_waitcnt vmcnt(1)" ::: "memory");
  __builtin_amdgcn_sched_barrier(0);
  COMPUTE(34, 1)
  __builtin_amdgcn_sched_barrier(0);
  asm volatile("s_waitcnt vmcnt(0)" ::: "memory");
  __builtin_amdgcn_sched_barrier(0);
  COMPUTE(35, 2)
#undef RUN
#undef COMPUTE
#undef STAGE
#undef STAGE_PATCH

  __syncthreads();   // all patch reads done; reuse patch as output buffer

  // Fused BN stat partials: shuffle-reduce over the 16 pixel lanes; the
  // (wv,lgrp,r) writer for each channel is unique -> direct store.
  {
    f32x4 sv4 = {0.f, 0.f, 0.f, 0.f}, qv4 = {0.f, 0.f, 0.f, 0.f};
    #pragma unroll
    for (int nf = 0; nf < 28; ++nf) {
      const f32x4 v = acc[nf];
      sv4 += v;
      qv4 += v * v;
    }
    #pragma unroll
    for (int r = 0; r < 4; ++r) {
      float sv = sv4[r], qv = qv4[r];
      sv += __shfl_xor(sv, 1, 64);  qv += __shfl_xor(qv, 1, 64);
      sv += __shfl_xor(sv, 2, 64);  qv += __shfl_xor(qv, 2, 64);
      sv += __shfl_xor(sv, 4, 64);  qv += __shfl_xor(qv, 4, 64);
      sv += __shfl_xor(sv, 8, 64);  qv += __shfl_xor(qv, 8, 64);
      if (lrow == 0) {
        const int ch = wv * 16 + lgrp * 4 + r;
        sacc[ch] = sv;
        sacc[CH + ch] = qv;
      }
    }
  }

  // Epilogue: two 224-px passes through obuf (57,344B <= patch region).
  char* obuf = (char*)patch;
  #pragma unroll
  for (int a = 0; a < 2; ++a) {
    if (a) __syncthreads();            // previous copy-out reads done
    #pragma unroll
    for (int m = 0; m < 14; ++m) {
      const f32x4 v = acc[a * 14 + m];
      bfv4 pk;
      #pragma unroll
      for (int r = 0; r < 4; ++r) pk[r] = f2bf(v[r]);
      const int p = (m * 2 + pyl) * 8 + px;            // 0..223 within pass
      const int ch = wv * 16 + lgrp * 4;
      int byte = p * 256 + ch * 2;
      byte ^= ((byte >> 8) & 3) << 5;
      *(bfv4*)(obuf + byte) = pk;
    }
    __syncthreads();
    if (a == 0 && t < 256) partials[(size_t)blockIdx.x * 256 + t] = sacc[t];
    // Copy out 224 px x 128 ch = 3584 x 16B units; h = a*28 + row.
    #pragma unroll
    for (int j = 0; j < 7; ++j) {
      const int u = j * 512 + t;
      int byte = u * 16;
      byte ^= ((byte >> 8) & 3) << 5;
      const bfv8 v = *(const bfv8*)(obuf + byte);
      const int pix = u >> 4, py = pix >> 3, pxx = pix & 7;
      *(bfv8*)(outp + ((size_t)((b * HH + a * 28 + py) * WW + (w0 + pxx))) * CH +
               (u & 15) * 8) = v;
    }
  }
}

// ---------------------------------------------------------------------------
// K-red: reduce partials[448][256] -> st[256]. 32 blocks x 256 thr.
__global__ __launch_bounds__(256)
void stat_reduce(const float* __restrict__ partials, float* __restrict__ st) {
  const int t = threadIdx.x;
  float s = 0.0f;
  const int i0 = blockIdx.x * (NCONVBLK / 32);
  for (int i = 0; i < NCONVBLK / 32; ++i)
    s += partials[(size_t)(i0 + i) * 256 + t];
  atomicAdd(&st[t], s);
}

// ---------------------------------------------------------------------------
// K4/K6: per-channel BN stats -> scale/shift tables.
__global__ __launch_bounds__(128)
void bn_stats(const float* __restrict__ st, const float* __restrict__ gamma,
              const float* __restrict__ beta, float* __restrict__ tab) {
  const int c = threadIdx.x;
  const float inv = 1.0f / NPIXF;
  const float mean = st[c] * inv;
  const float var = st[CH + c] * inv - mean * mean;
  const float s = gamma[c] / sqrtf(var + 1e-5f);
  tab[c] = s;
  tab[CH + c] = beta[c] - mean * s;
}

// ---------------------------------------------------------------------------
// K7 (R23, verified): out = relu(scale2*y2 + shift2 + residual), NHWC bf16
// -> NCHW fp32 via LDS transpose. Coalesced channel reads (bfv8), transposed
// tile[c][113], coalesced w-contiguous NCHW writes. 2 h-rows/block.
template<bool BF16RES>
__global__ __launch_bounds__(256)
void final_kernel(const unsigned short* __restrict__ y2,
                  const unsigned short* __restrict__ xbf,
                  const float* __restrict__ x,
                  const float* __restrict__ tab, float* __restrict__ out) {
  __shared__ float tile[CH * 113];                  // [c][pos], pos 0..111
  const int bid = blockIdx.x;
  const int b = bid / 28, hp = bid % 28;
  const int h0 = hp * 2;
  const int t = threadIdx.x;

  if (t < 224) {                                    // pix 0..111, half 0..1
    const int pix = t >> 1, half = t & 1;
    const int h = h0 + pix / 56, w = pix % 56;
    const size_t base = ((size_t)((b * HH + h) * WW + w)) * CH + half * 64;
    const unsigned short* ys = y2 + base;
    const unsigned short* rs = xbf + base;
    const float* xs = x + (size_t)b * CH * HWPIX + h * WW + w;
    #pragma unroll
    for (int j = 0; j < 8; ++j) {
      const bfv8 v = *(const bfv8*)(ys + j * 8);
      bfv8 r;
      if (BF16RES) r = *(const bfv8*)(rs + j * 8);
      #pragma unroll
      for (int k = 0; k < 8; ++k) {
        const int c = half * 64 + j * 8 + k;
        const float res = BF16RES ? bf2f(r[k]) : xs[(size_t)c * HWPIX];
        tile[c * 113 + pix] =
            fmaxf(bf2f(v[k]) * tab[c] + tab[CH + c] + res, 0.0f);
      }
    }
  }
  __syncthreads();

  const int w = t & 63, hl = (t >> 6) & 1, cg = t >> 7;  // cg 0..1
  if (w < WW) {
    const int pos = hl * 56 + w;
    float* os = out + (size_t)b * CH * HWPIX + (size_t)(h0 + hl) * WW + w;
    #pragma unroll
    for (int c0 = 0; c0 < 64; ++c0) {
      const int c = cg * 64 + c0;
      os[(size_t)c * HWPIX] = tile[c * 113 + pos];
    }
  }
}

// ---------------------------------------------------------------------------
extern "C" void kernel_launch(void* const* d_in, const int* in_sizes, int n_in,
                              void* d_out, int out_size, void* d_ws, size_t ws_size,
                              hipStream_t stream) {
  const float* x  = (const float*)d_in[0];
  const float* w1 = (const float*)d_in[1];
  const float* w2 = (const float*)d_in[2];
  const float* g1 = (const float*)d_in[3];
  const float* b1 = (const float*)d_in[4];
  const float* g2 = (const float*)d_in[5];
  const float* b2 = (const float*)d_in[6];
  float* out = (float*)d_out;

  // Workspace layout (bytes):
  //   xT   0            51,380,224
  //   y1   51,380,224   51,380,224
  //   w1b  102,760,448  18,874,368
  //   w2b  121,634,816  18,874,368
  //   p1   140,509,184  3,211,264   (448 x 256 floats used)
  //   p2   143,720,448  3,211,264
  //   st   146,931,712  4,096   (st1|st2|tab1|tab2, 256 floats each)
  //   y2   146,935,808  51,380,224  (optional, if ws_size allows)
  char* ws = (char*)d_ws;
  unsigned short* xT  = (unsigned short*)(ws);
  unsigned short* y1  = (unsigned short*)(ws + 51380224);
  unsigned short* w1b = (unsigned short*)(ws + 102760448);
  unsigned short* w2b = (unsigned short*)(ws + 121634816);
  float*          p1  = (float*)(ws + 140509184);
  float*          p2  = (float*)(ws + 143720448);
  float*          st  = (float*)(ws + 146931712);
  const bool sepY2 = ws_size >= (size_t)146935808 + 51380224;
  unsigned short* y2  = sepY2 ? (unsigned short*)(ws + 146935808) : xT;

  (void)hipMemsetAsync(st, 0, 2048, stream);  // zero st1+st2

  hipLaunchKernelGGL(prep_x, dim3(NB * 14), dim3(256), 0, stream, x, xT);
  hipLaunchKernelGGL(prep_w, dim3(1024), dim3(256), 0, stream, w1, w2, w1b, w2b);
  hipLaunchKernelGGL((conv_kernel<false>), dim3(NCONVBLK), dim3(512), 0, stream,
                     xT, w1b, y1, p1, (const float*)nullptr);
  hipLaunchKernelGGL(stat_reduce, dim3(32), dim3(256), 0, stream, p1, st);
  hipLaunchKernelGGL(bn_stats, dim3(1), dim3(128), 0, stream, st, g1, b1, st + 512);
  hipLaunchKernelGGL((conv_kernel<true>), dim3(NCONVBLK), dim3(512), 0, stream,
                     y1, w2b, y2, p2, st + 512);
  hipLaunchKernelGGL(stat_reduce, dim3(32), dim3(256), 0, stream, p2, st + 256);
  hipLaunchKernelGGL(bn_stats, dim3(1), dim3(128), 0, stream, st + 256, g2, b2, st + 768);
  if (sepY2) {
    hipLaunchKernelGGL((final_kernel<true>), dim3(NB * 28), dim3(256), 0, stream,
                       y2, xT, x, st + 768, out);
  } else {
    hipLaunchKernelGGL((final_kernel<false>), dim3(NB * 28), dim3(256), 0, stream,
                       y2, xT, x, st + 768, out);
  }
}

// Round 19
// 273.175 us; speedup vs baseline: 1.2899x; 1.2899x over previous
//
#include <hip/hip_runtime.h>
#include <hip/hip_bf16.h>
#include <stdint.h>
#include <stddef.h>

// Problem dims (fixed): B=64, C=128, H=W=56, 3x3 conv pad=1 stride=1.
#define CH 128
#define HH 56
#define WW 56
#define HWPIX (HH*WW)        // 3136
#define NB 64
#define NPIXF 200704.0f      // B*H*W
#define NCONVBLK 896         // 64 samples x 14 tiles (28x8 px)
#define PSTR 72              // patch row stride in shorts (144B = 4-bank class)

typedef __attribute__((ext_vector_type(8))) short short8v;    // 8 bf16 -> MFMA A/B frag
typedef __attribute__((ext_vector_type(8))) unsigned short bfv8;
typedef __attribute__((ext_vector_type(4))) unsigned short bfv4;
typedef __attribute__((ext_vector_type(4))) float f32x4;

__device__ __forceinline__ unsigned short f2bf(float f) {
  unsigned int u = __float_as_uint(f);
  u += 0x7fffu + ((u >> 16) & 1u);            // RNE
  return (unsigned short)(u >> 16);
}
__device__ __forceinline__ float bf2f(unsigned short s) {
  return __uint_as_float(((unsigned int)s) << 16);
}

// ---------------------------------------------------------------------------
// K1: x NCHW fp32 -> NHWC bf16 (LDS transpose, coalesced 16B/lane writes).
__global__ __launch_bounds__(256)
void prep_x(const float* __restrict__ x, unsigned short* __restrict__ xT) {
  __shared__ unsigned short tile[4 * 56 * 128];
  const int bid = blockIdx.x;
  const int b = bid / 14, hq = bid % 14;
  const int hl = threadIdx.x >> 6;
  const int h = hq * 4 + hl;
  const int w = threadIdx.x & 63;
  if (w < WW) {
    const float* src = x + (size_t)b * CH * HWPIX + h * WW + w;
    const int pos = hl * WW + w;
    #pragma unroll 4
    for (int c0 = 0; c0 < CH; c0 += 8) {
      bfv8 v;
      #pragma unroll
      for (int k = 0; k < 8; ++k) v[k] = f2bf(src[(size_t)(c0 + k) * HWPIX]);
      const int idx = (pos * CH + c0) ^ ((pos & 7) << 3);
      *(bfv8*)(tile + idx) = v;
    }
  }
  __syncthreads();
  unsigned short* out = xT + (size_t)(b * HH + hq * 4) * WW * CH;
  #pragma unroll
  for (int j = 0; j < 14; ++j) {
    const int u = j * 256 + threadIdx.x;
    const int idx = (u * 8) ^ (((u >> 4) & 7) << 3);
    *(bfv8*)(out + u * 8) = *(const bfv8*)(tile + idx);
  }
}

// ---------------------------------------------------------------------------
// K2: weights [B,O,I,3,3] fp32 -> [B,tap,O,I] bf16 (dense reads, 16B writes).
__global__ __launch_bounds__(256)
void prep_w(const float* __restrict__ w1, const float* __restrict__ w2,
            unsigned short* __restrict__ o1, unsigned short* __restrict__ o2) {
  __shared__ unsigned short lw[18432];
  const int id = blockIdx.x;
  const int which = id >> 9;
  const int b = (id >> 3) & 63, ck = id & 7;
  const float* src = (which ? w2 : w1) + ((size_t)b * 16384 + ck * 2048) * 9;
  unsigned short* dst = (which ? o2 : o1);
  const int t = threadIdx.x;
  #pragma unroll
  for (int j = 0; j < 72; ++j)
    lw[j * 256 + t] = f2bf(src[j * 256 + t]);
  __syncthreads();
  const int ol = t >> 4, oct = t & 15;
  #pragma unroll
  for (int tap = 0; tap < 9; ++tap) {
    bfv8 v;
    #pragma unroll
    for (int k = 0; k < 8; ++k) v[k] = lw[(ol * 128 + oct * 8 + k) * 9 + tap];
    *(bfv8*)(dst + ((size_t)(b * 9 + tap) * CH + ck * 16 + ol) * CH + oct * 8) = v;
  }
}

// ---------------------------------------------------------------------------
// K3/K5: per-sample conv, implicit GEMM — R24 CONFIGURATION RESTORED (the
// session best: conv 87.5us, total 274.7us). R26's 56x8/8-wave attempt was
// correct but regressed (conv 128us: bank conflicts 15.65M->30.1M from 8
// waves sharing one patch; gll lever exhausted). 28x8 tile + K-split patch
// (PSTR=72): gll count 1008/CU + 2 blocks/CU co-residency simultaneously.
template<bool FUSE>
__global__ __launch_bounds__(256, 2)
void conv_kernel(const unsigned short* __restrict__ in,
                 const unsigned short* __restrict__ wt,
                 unsigned short* __restrict__ outp,
                 float* __restrict__ partials,
                 const float* __restrict__ tab) {   // [256]: scale | shift (FUSE)
  __shared__ __align__(16) unsigned short patch[300 * PSTR]; // 300 pos x 64ch
  __shared__ __align__(16) unsigned short wbuf[12288];   // 4 wv x 3 buf x 1024
  __shared__ float sacc[256];                            // sum[128] | sumsq[128]
  const int xcd = blockIdx.x & 7;
  const int q = blockIdx.x >> 3;                    // 0..111
  const int s = q / 14;
  const int tile = q - s * 14;                      // 0..13
  const int b = s * 8 + xcd;
  const int ty = tile / 7, tx = tile % 7;
  const int h0 = ty * 28, w0 = tx * 8;
  const int t = threadIdx.x;

  const int lane = t & 63, wv = t >> 6;
  const int lrow = lane & 15, lgrp = lane >> 4;
  const int px = lrow & 7, pyl = lrow >> 3;

  sacc[t] = 0.0f;

  // Per-lane global source = lane's A-frag: W[o=wv*32+lrow][lgrp*8..+8].
  const unsigned short* wsrc =
      wt + (size_t)b * 9 * CH * CH + (wv * 32 + lrow) * CH + lgrp * 8;

  // Stage S (0..35): phase = S/18, tap = (S%18)>>1, ic = phase*64+(S&1)*32.
  // 32 O x 32 I = 2KB/wave into wave-private buffer P (2 gll instrs).
#define STAGE(S, P) { \
    const unsigned short* g_ = wsrc + (((S) % 18) >> 1) * (CH * CH) + \
                               ((S) / 18) * 64 + ((S) & 1) * 32; \
    unsigned short* l_ = wbuf + (wv * 3 + (P)) * 1024; \
    __builtin_amdgcn_global_load_lds( \
        (const __attribute__((address_space(1))) void*)g_, \
        (__attribute__((address_space(3))) void*)l_, 16, 0, 0); \
    __builtin_amdgcn_global_load_lds( \
        (const __attribute__((address_space(1))) void*)(g_ + 16 * CH), \
        (__attribute__((address_space(3))) void*)(l_ + 512), 16, 0, 0); \
  }

  // Patch staging for channel-half PH: 300 positions x 64 ch (128B each).
#define STAGE_PATCH(PH) { \
    for (int u = t; u < 300; u += 256) { \
      const int dh = u / 10, dw = u - dh * 10; \
      const int h = h0 + dh - 1, w = w0 + dw - 1; \
      unsigned short* ld = &patch[u * PSTR]; \
      if (h >= 0 && h < HH && w >= 0 && w < WW) { \
        const unsigned short* src = \
            in + ((size_t)((b * HH + h) * WW + w)) * CH + (PH) * 64; \
        if (FUSE) { \
          for (int j = 0; j < 8; ++j) { \
            const bfv8 v = *(const bfv8*)(src + j * 8); \
            bfv8 o; \
            for (int k = 0; k < 8; ++k) { \
              const int c = (PH) * 64 + j * 8 + k; \
              o[k] = f2bf(fmaxf(bf2f(v[k]) * tab[c] + tab[CH + c], 0.0f)); \
            } \
            *(bfv8*)(ld + j * 8) = o; \
          } \
        } else { \
          for (int j = 0; j < 8; ++j) \
            *(bfv8*)(ld + j * 8) = *(const bfv8*)(src + j * 8); \
        } \
      } else { \
        const bfv8 z = {0, 0, 0, 0, 0, 0, 0, 0}; \
        for (int j = 0; j < 8; ++j) *(bfv8*)(ld + j * 8) = z; \
      } \
    } }

  // COMPUTE(S,P): 2 A-frags lane-linear from wave-private buf P,
  // 14 B-frags from patch (ic chunk = S&1 within the 64-wide rows), 28 MFMA.
#define COMPUTE(S, P) { \
    const int tap_ = ((S) % 18) >> 1, icl_ = (S) & 1; \
    const int pb_ = (pyl + tap_ / 3) * 10 + px + tap_ % 3; \
    const unsigned short* ab_ = wbuf + (wv * 3 + (P)) * 1024 + lane * 8; \
    const short8v a0_ = *(const short8v*)(ab_); \
    const short8v a1_ = *(const short8v*)(ab_ + 512); \
    _Pragma("unroll") \
    for (int nf = 0; nf < 14; ++nf) { \
      const short8v bfr = *(const short8v*)( \
          &patch[(pb_ + nf * 20) * PSTR + icl_ * 32 + lgrp * 8]); \
      acc[0][nf] = __builtin_amdgcn_mfma_f32_16x16x32_bf16(a0_, bfr, acc[0][nf], 0, 0, 0); \
      acc[1][nf] = __builtin_amdgcn_mfma_f32_16x16x32_bf16(a1_, bfr, acc[1][nf], 0, 0, 0); \
    } }

#define RUN(S) \
    __builtin_amdgcn_sched_barrier(0); \
    STAGE((S) + 2, ((S) + 2) % 3) \
    asm volatile("s_waitcnt vmcnt(4)" ::: "memory"); \
    __builtin_amdgcn_sched_barrier(0); \
    COMPUTE(S, (S) % 3)

  // ---- Phase 0: I in [0,64) ----
  STAGE(0, 0)
  STAGE_PATCH(0)
  __syncthreads();

  f32x4 acc[2][14];
  #pragma unroll
  for (int m = 0; m < 2; ++m)
    #pragma unroll
    for (int n = 0; n < 14; ++n) acc[m][n] = (f32x4){0.f, 0.f, 0.f, 0.f};

  STAGE(1, 1)
  RUN(0)  RUN(1)  RUN(2)  RUN(3)  RUN(4)  RUN(5)  RUN(6)  RUN(7)
  RUN(8)  RUN(9)  RUN(10) RUN(11) RUN(12) RUN(13) RUN(14) RUN(15)
  __builtin_amdgcn_sched_barrier(0);
  asm volatile("s_waitcnt vmcnt(2)" ::: "memory");
  __builtin_amdgcn_sched_barrier(0);
  COMPUTE(16, 1)
  __builtin_amdgcn_sched_barrier(0);
  asm volatile("s_waitcnt vmcnt(0)" ::: "memory");
  __builtin_amdgcn_sched_barrier(0);
  COMPUTE(17, 2)

  // ---- Phase boundary: restage patch with I in [64,128) ----
  STAGE(18, 0)            // drained resident by the barrier below
  __syncthreads();        // all phase-0 patch reads done
  STAGE_PATCH(1)
  __syncthreads();        // new patch ready

  STAGE(19, 1)
  RUN(18) RUN(19) RUN(20) RUN(21) RUN(22) RUN(23) RUN(24) RUN(25)
  RUN(26) RUN(27) RUN(28) RUN(29) RUN(30) RUN(31) RUN(32) RUN(33)
  __builtin_amdgcn_sched_barrier(0);
  asm volatile("s_waitcnt vmcnt(2)" ::: "memory");
  __builtin_amdgcn_sched_barrier(0);
  COMPUTE(34, 1)
  __builtin_amdgcn_sched_barrier(0);
  asm volatile("s_waitcnt vmcnt(0)" ::: "memory");
  __builtin_amdgcn_sched_barrier(0);
  COMPUTE(35, 2)
#undef RUN
#undef COMPUTE
#undef STAGE
#undef STAGE_PATCH

  __syncthreads();   // all patch reads done; reuse patch as output buffer

  // Fused BN stat partials (uses acc only; sacc atomics complete before the
  // next barrier).
  #pragma unroll
  for (int mf = 0; mf < 2; ++mf) {
    f32x4 sv4 = {0.f, 0.f, 0.f, 0.f}, qv4 = {0.f, 0.f, 0.f, 0.f};
    #pragma unroll
    for (int nf = 0; nf < 14; ++nf) {
      const f32x4 v = acc[mf][nf];
      sv4 += v;
      qv4 += v * v;
    }
    #pragma unroll
    for (int r = 0; r < 4; ++r) {
      float sv = sv4[r], qv = qv4[r];
      sv += __shfl_xor(sv, 1, 64);  qv += __shfl_xor(qv, 1, 64);
      sv += __shfl_xor(sv, 2, 64);  qv += __shfl_xor(qv, 2, 64);
      sv += __shfl_xor(sv, 4, 64);  qv += __shfl_xor(qv, 4, 64);
      sv += __shfl_xor(sv, 8, 64);  qv += __shfl_xor(qv, 8, 64);
      if (lrow == 0) {
        const int ch = wv * 32 + mf * 16 + lgrp * 4 + r;
        atomicAdd(&sacc[ch], sv);
        atomicAdd(&sacc[CH + ch], qv);
      }
    }
  }

  // Epilogue: two 112-px passes through obuf (28,672B <= patch region).
  char* obuf = (char*)patch;
  #pragma unroll
  for (int a = 0; a < 2; ++a) {
    if (a) __syncthreads();            // previous copy-out reads done
    #pragma unroll
    for (int mf = 0; mf < 2; ++mf) {
      #pragma unroll
      for (int m = 0; m < 7; ++m) {
        const f32x4 v = acc[mf][a * 7 + m];
        bfv4 pk;
        #pragma unroll
        for (int r = 0; r < 4; ++r) pk[r] = f2bf(v[r]);
        const int p = (m * 2 + pyl) * 8 + px;          // 0..111 within pass
        const int ch = wv * 32 + mf * 16 + lgrp * 4;
        int byte = p * 256 + ch * 2;
        byte ^= ((byte >> 8) & 3) << 5;
        *(bfv4*)(obuf + byte) = pk;
      }
    }
    __syncthreads();
    if (a == 0) partials[(size_t)blockIdx.x * 256 + t] = sacc[t];
    // Copy out 112 px x 128 ch = 1792 x 16B units.
    #pragma unroll
    for (int j = 0; j < 7; ++j) {
      const int u = j * 256 + t;
      int byte = u * 16;
      byte ^= ((byte >> 8) & 3) << 5;
      const bfv8 v = *(const bfv8*)(obuf + byte);
      const int pix = u >> 4, py = pix >> 3, pxx = pix & 7;
      *(bfv8*)(outp + ((size_t)((b * HH + h0 + a * 14 + py) * WW + (w0 + pxx))) * CH +
               (u & 15) * 8) = v;
    }
  }
}

// ---------------------------------------------------------------------------
// K-red: reduce partials[896][256] -> st[256]. 32 blocks x 256 thr.
__global__ __launch_bounds__(256)
void stat_reduce(const float* __restrict__ partials, float* __restrict__ st) {
  const int t = threadIdx.x;
  float s = 0.0f;
  const int i0 = blockIdx.x * (NCONVBLK / 32);
  for (int i = 0; i < NCONVBLK / 32; ++i)
    s += partials[(size_t)(i0 + i) * 256 + t];
  atomicAdd(&st[t], s);
}

// ---------------------------------------------------------------------------
// K4/K6: per-channel BN stats -> scale/shift tables.
__global__ __launch_bounds__(128)
void bn_stats(const float* __restrict__ st, const float* __restrict__ gamma,
              const float* __restrict__ beta, float* __restrict__ tab) {
  const int c = threadIdx.x;
  const float inv = 1.0f / NPIXF;
  const float mean = st[c] * inv;
  const float var = st[CH + c] * inv - mean * mean;
  const float s = gamma[c] / sqrtf(var + 1e-5f);
  tab[c] = s;
  tab[CH + c] = beta[c] - mean * s;
}

// ---------------------------------------------------------------------------
// K7 (R23, verified): out = relu(scale2*y2 + shift2 + residual), NHWC bf16
// -> NCHW fp32 via LDS transpose. Coalesced channel reads (bfv8), transposed
// tile[c][113], coalesced w-contiguous NCHW writes. 2 h-rows/block.
template<bool BF16RES>
__global__ __launch_bounds__(256)
void final_kernel(const unsigned short* __restrict__ y2,
                  const unsigned short* __restrict__ xbf,
                  const float* __restrict__ x,
                  const float* __restrict__ tab, float* __restrict__ out) {
  __shared__ float tile[CH * 113];                  // [c][pos], pos 0..111
  const int bid = blockIdx.x;
  const int b = bid / 28, hp = bid % 28;
  const int h0 = hp * 2;
  const int t = threadIdx.x;

  if (t < 224) {                                    // pix 0..111, half 0..1
    const int pix = t >> 1, half = t & 1;
    const int h = h0 + pix / 56, w = pix % 56;
    const size_t base = ((size_t)((b * HH + h) * WW + w)) * CH + half * 64;
    const unsigned short* ys = y2 + base;
    const unsigned short* rs = xbf + base;
    const float* xs = x + (size_t)b * CH * HWPIX + h * WW + w;
    #pragma unroll
    for (int j = 0; j < 8; ++j) {
      const bfv8 v = *(const bfv8*)(ys + j * 8);
      bfv8 r;
      if (BF16RES) r = *(const bfv8*)(rs + j * 8);
      #pragma unroll
      for (int k = 0; k < 8; ++k) {
        const int c = half * 64 + j * 8 + k;
        const float res = BF16RES ? bf2f(r[k]) : xs[(size_t)c * HWPIX];
        tile[c * 113 + pix] =
            fmaxf(bf2f(v[k]) * tab[c] + tab[CH + c] + res, 0.0f);
      }
    }
  }
  __syncthreads();

  const int w = t & 63, hl = (t >> 6) & 1, cg = t >> 7;  // cg 0..1
  if (w < WW) {
    const int pos = hl * 56 + w;
    float* os = out + (size_t)b * CH * HWPIX + (size_t)(h0 + hl) * WW + w;
    #pragma unroll
    for (int c0 = 0; c0 < 64; ++c0) {
      const int c = cg * 64 + c0;
      os[(size_t)c * HWPIX] = tile[c * 113 + pos];
    }
  }
}

// ---------------------------------------------------------------------------
extern "C" void kernel_launch(void* const* d_in, const int* in_sizes, int n_in,
                              void* d_out, int out_size, void* d_ws, size_t ws_size,
                              hipStream_t stream) {
  const float* x  = (const float*)d_in[0];
  const float* w1 = (const float*)d_in[1];
  const float* w2 = (const float*)d_in[2];
  const float* g1 = (const float*)d_in[3];
  const float* b1 = (const float*)d_in[4];
  const float* g2 = (const float*)d_in[5];
  const float* b2 = (const float*)d_in[6];
  float* out = (float*)d_out;

  // Workspace layout (bytes):
  //   xT   0            51,380,224
  //   y1   51,380,224   51,380,224
  //   w1b  102,760,448  18,874,368
  //   w2b  121,634,816  18,874,368
  //   p1   140,509,184  3,211,264   (896 x 256 floats used)
  //   p2   143,720,448  3,211,264
  //   st   146,931,712  4,096   (st1|st2|tab1|tab2, 256 floats each)
  //   y2   146,935,808  51,380,224  (optional, if ws_size allows)
  char* ws = (char*)d_ws;
  unsigned short* xT  = (unsigned short*)(ws);
  unsigned short* y1  = (unsigned short*)(ws + 51380224);
  unsigned short* w1b = (unsigned short*)(ws + 102760448);
  unsigned short* w2b = (unsigned short*)(ws + 121634816);
  float*          p1  = (float*)(ws + 140509184);
  float*          p2  = (float*)(ws + 143720448);
  float*          st  = (float*)(ws + 146931712);
  const bool sepY2 = ws_size >= (size_t)146935808 + 51380224;
  unsigned short* y2  = sepY2 ? (unsigned short*)(ws + 146935808) : xT;

  (void)hipMemsetAsync(st, 0, 2048, stream);  // zero st1+st2

  hipLaunchKernelGGL(prep_x, dim3(NB * 14), dim3(256), 0, stream, x, xT);
  hipLaunchKernelGGL(prep_w, dim3(1024), dim3(256), 0, stream, w1, w2, w1b, w2b);
  hipLaunchKernelGGL((conv_kernel<false>), dim3(NCONVBLK), dim3(256), 0, stream,
                     xT, w1b, y1, p1, (const float*)nullptr);
  hipLaunchKernelGGL(stat_reduce, dim3(32), dim3(256), 0, stream, p1, st);
  hipLaunchKernelGGL(bn_stats, dim3(1), dim3(128), 0, stream, st, g1, b1, st + 512);
  hipLaunchKernelGGL((conv_kernel<true>), dim3(NCONVBLK), dim3(256), 0, stream,
                     y1, w2b, y2, p2, st + 512);
  hipLaunchKernelGGL(stat_reduce, dim3(32), dim3(256), 0, stream, p2, st + 256);
  hipLaunchKernelGGL(bn_stats, dim3(1), dim3(128), 0, stream, st + 256, g2, b2, st + 768);
  if (sepY2) {
    hipLaunchKernelGGL((final_kernel<true>), dim3(NB * 28), dim3(256), 0, stream,
                       y2, xT, x, st + 768, out);
  } else {
    hipLaunchKernelGGL((final_kernel<false>), dim3(NB * 28), dim3(256), 0, stream,
                       y2, xT, x, st + 768, out);
  }
}